// Round 4
// baseline (340.985 us; speedup 1.0000x reference)
//
#include <hip/hip_runtime.h>

// Problem constants
#define B_   2
#define NQ_  8192
#define NK_  8192
#define DIN_ 256
#define DH_  256
#define M_   (B_ * NQ_)   // 16384 flattened rows

typedef _Float16 f16x8 __attribute__((ext_vector_type(8)));
typedef unsigned short u16x8 __attribute__((ext_vector_type(8)));
typedef unsigned short u16x4 __attribute__((ext_vector_type(4)));
typedef unsigned int  u32x4 __attribute__((ext_vector_type(4)));
typedef float f32x16 __attribute__((ext_vector_type(16)));

// fp32 -> fp16 bits (RTNE via hardware cvt)
__device__ __forceinline__ unsigned short f2h(float f) {
    _Float16 h = (_Float16)f;
    return __builtin_bit_cast(unsigned short, h);
}
__device__ __forceinline__ float h2f(unsigned short u) {
    return (float)__builtin_bit_cast(_Float16, u);
}

// LDS-only barrier: drain DS ops, leave VMEM (K-DMA + vf loads) in flight.
__device__ __forceinline__ void lgkm_barrier() {
    __builtin_amdgcn_sched_barrier(0);
    asm volatile("s_waitcnt lgkmcnt(0)" ::: "memory");
    __builtin_amdgcn_s_barrier();
    __builtin_amdgcn_sched_barrier(0);
}
// Counted barrier: drain the 8 oldest VMEM ops (the K-DMAs; FIFO order) so the
// next K tile is visible to ALL waves after the barrier, while the 16 vf loads
// (issued after the DMAs) stay in flight for PV's register-dependency wait.
__device__ __forceinline__ void vm16_lgkm_barrier() {
    __builtin_amdgcn_sched_barrier(0);
    asm volatile("s_waitcnt vmcnt(16) lgkmcnt(0)" ::: "memory");
    __builtin_amdgcn_s_barrier();
    __builtin_amdgcn_sched_barrier(0);
}

// ---------------------------------------------------------------------------
// Kernel 1: weight convert + transpose via LDS tile (both sides coalesced).
// wt[mat][n][k] = fp16(W[mat][k][n]).  grid (4,4,3), block 256.  (unchanged)
// ---------------------------------------------------------------------------
__global__ void wt_conv(const float* __restrict__ Wq, const float* __restrict__ Wk,
                        const float* __restrict__ Wv, unsigned short* __restrict__ wt) {
    __shared__ float tile[64][65];
    const int mat = blockIdx.z;
    const int k0 = blockIdx.x * 64, n0 = blockIdx.y * 64;
    const float* W = (mat == 0) ? Wq : (mat == 1) ? Wk : Wv;
#pragma unroll
    for (int p = 0; p < 16; ++p) {
        const int idx = p * 256 + threadIdx.x;
        const int r = idx >> 6, c = idx & 63;
        tile[r][c] = W[(k0 + r) * 256 + n0 + c];
    }
    __syncthreads();
#pragma unroll
    for (int p = 0; p < 16; ++p) {
        const int idx = p * 256 + threadIdx.x;
        const int nr = idx >> 6, kc = idx & 63;
        wt[mat * 65536 + (n0 + nr) * 256 + k0 + kc] = f2h(tile[kc][nr]);
    }
}

// ---------------------------------------------------------------------------
// Kernel 2: projections (unchanged from v4).
// mat 2 (v): fragment-packed vpack[b][kt][dg][lane][j]; flash PV A-operand
// loads are contiguous 1KB per wave.
// ---------------------------------------------------------------------------
__global__ __launch_bounds__(256) void proj(
    const float* __restrict__ xq, const float* __restrict__ xk, const float* __restrict__ xv,
    const float* __restrict__ bq, const float* __restrict__ bk, const float* __restrict__ bv,
    const unsigned short* __restrict__ wt,
    unsigned short* __restrict__ q_emb, unsigned short* __restrict__ k_emb,
    unsigned short* __restrict__ vpack) {
    const int mat = blockIdx.y;
    const float* x    = (mat == 0) ? xq : (mat == 1) ? xk : xv;
    const float* bias = (mat == 0) ? bq : (mat == 1) ? bk : bv;
    const unsigned short* w = wt + mat * 65536;

    const int tid = threadIdx.x;
    const int l = tid & 63, wv = tid >> 6;
    const int pair = wv >> 1, h = wv & 1;
    const int lm = l & 31, lh = l >> 5;
    const int row0 = blockIdx.x * 64;
    const int m = row0 + pair * 32 + lm;

    f32x16 acc[4];
#pragma unroll
    for (int i = 0; i < 4; ++i)
#pragma unroll
        for (int j = 0; j < 16; ++j) acc[i][j] = 0.0f;

#pragma unroll
    for (int ks = 0; ks < 16; ++ks) {
        const float4* ap = (const float4*)(x + (size_t)m * 256 + ks * 16 + lh * 8);
        float4 a0 = ap[0], a1 = ap[1];
        u16x8 au;
        au[0] = f2h(a0.x); au[1] = f2h(a0.y); au[2] = f2h(a0.z); au[3] = f2h(a0.w);
        au[4] = f2h(a1.x); au[5] = f2h(a1.y); au[6] = f2h(a1.z); au[7] = f2h(a1.w);
        f16x8 af = __builtin_bit_cast(f16x8, au);
#pragma unroll
        for (int nt = 0; nt < 4; ++nt) {
            f16x8 bfr = *(const f16x8*)(w + (h * 128 + nt * 32 + lm) * 256 + ks * 16 + lh * 8);
            acc[nt] = __builtin_amdgcn_mfma_f32_32x32x16_f16(af, bfr, acc[nt], 0, 0, 0);
        }
    }

    if (mat < 2) {
        unsigned short* emb = (mat == 0) ? q_emb : k_emb;
#pragma unroll
        for (int nt = 0; nt < 4; ++nt) {
            const int n = h * 128 + nt * 32 + lm;
            const float bsv = bias[n];
#pragma unroll
            for (int r = 0; r < 16; ++r) {
                const int rl = (r & 3) + 8 * (r >> 2) + 4 * lh;
                emb[(size_t)(row0 + pair * 32 + rl) * 256 + n] = f2h(acc[nt][r] + bsv);
            }
        }
    } else {
        const int batch = row0 >> 13;
        const int m0 = (row0 & 8191) + pair * 32;   // v-row (k index) base
        unsigned short* vp = vpack + (size_t)batch * (512 * 8 * 64 * 8);
        const int base_kt = m0 >> 4;
#pragma unroll
        for (int nt = 0; nt < 4; ++nt) {
            const int dg = h * 4 + nt;              // d-group = n >> 5
            const int n = h * 128 + nt * 32 + lm;
            const float bsv = bias[n];
#pragma unroll
            for (int g = 0; g < 4; ++g) {
                u16x4 pk;
#pragma unroll
                for (int i = 0; i < 4; ++i) pk[i] = f2h(acc[nt][4 * g + i] + bsv);
                const int kt = base_kt + (g >> 1);
                const int lane = (g & 1) * 32 + lm;
                *(u16x4*)(vp + ((size_t)(kt * 8 + dg) * 64 + lane) * 8 + lh * 4) = pk;
            }
        }
    }
}

// ---------------------------------------------------------------------------
// Kernel 3: flash attention v5 = v4 + counted-vmcnt barriers (T4).
//   - B3: lgkm-only (smax is DS); K-DMA + vf loads sail across.
//   - B4: vmcnt(16)+lgkm: drains exactly the 8 older K-DMAs (next tile
//     guaranteed visible block-wide), leaves the 16 vf loads in flight;
//     they are drained by the register dependency inside PV.
//   Hazards audited: kbuf WAR via B3(t-1); pbuf WAR via B3(t+1); smax WAR
//   via B4(t); ssum WAR via B3(t+1); cross-wave DMA visibility via B4's
//   counted vmcnt (guarantee, not latency argument).
// ---------------------------------------------------------------------------
#define BN_ 128
#define NT_ (NK_ / BN_)                    // 64 iterations
#define KB_BYTES 65536                     // 128 rows x 512B (swizzled granules)
#define PSTRIDE 272                        // 64 rows x (256 + 16) : proven pad
#define PBYTES  (64 * PSTRIDE)             // 17408
#define STAT_OFF (2 * KB_BYTES + PBYTES)   // 148480
#define LDS_TOTAL (STAT_OFF + 2048)        // 150528 <= 160 KiB

__global__ __launch_bounds__(512, 2) void flash(
    const unsigned short* __restrict__ q_emb, const unsigned short* __restrict__ k_emb,
    const unsigned short* __restrict__ vpack, float* __restrict__ out) {
    __shared__ __align__(16) char lds_raw[LDS_TOTAL];
    char* pbuf = lds_raw + 2 * KB_BYTES;        // [64][272]
    float* smax = (float*)(lds_raw + STAT_OFF); // [2][32][4]
    float* ssum = smax + 256;                   // [2][32][4]

    const int tid = threadIdx.x;
    const int l = tid & 63, wv = tid >> 6;      // wv 0..7
    const int kq = wv >> 1, pair = wv & 1;      // k-tile / q-tile role
    const int lm = l & 31, lh = l >> 5;

    const int bx = blockIdx.x;
    const int batch = bx >> 7;
    const int qb = (bx & 127) * 64;

    const unsigned short* kg = k_emb + (size_t)batch * NK_ * 256;
    const unsigned short* vp = vpack + (size_t)batch * (512 * 8 * 64 * 8);

    // Q fragments register-resident: q row = qb + pair*32 + lm, all 256 dims.
    const int mrow = batch * NQ_ + qb + pair * 32 + lm;
    f16x8 qf[16];
#pragma unroll
    for (int ks = 0; ks < 16; ++ks)
        qf[ks] = *(const f16x8*)(q_emb + (size_t)mrow * 256 + ks * 16 + lh * 8);

    // O^T accumulator: this wave's d-quarter (kq), q cols = pair tile.
    f32x16 oacc[2];
#pragma unroll
    for (int i = 0; i < 2; ++i)
#pragma unroll
        for (int j = 0; j < 16; ++j) oacc[i][j] = 0.0f;

    float mstat = -3.0e38f, lstat = 0.0f;

    // ---- K staging via global_load_lds: wave wv owns rows wv*16..wv*16+15.
    // LDS[r][g] = global[r][g ^ (r&31)] (granule = 16B); dest linear per DMA
    // rules, swizzle on the per-lane SOURCE address.
    const int rlane = l >> 5;                  // +0/+1 row within 1KB chunk
    const int gl = l & 31;                     // linear granule this lane fills
    auto stage_k = [&](int kb, char* kdst) {
#pragma unroll
        for (int p = 0; p < 8; ++p) {
            const int r0 = wv * 16 + 2 * p;            // wave-uniform base row
            const int r = r0 + rlane;
            const int gsw = gl ^ (r & 31);             // source granule
            const unsigned short* src = kg + (size_t)(kb + r) * 256 + gsw * 8;
            __builtin_amdgcn_global_load_lds(
                (const __attribute__((address_space(1))) void*)src,
                (__attribute__((address_space(3))) void*)(kdst + r0 * 512),
                16, 0, 0);
        }
    };

    // ---- V fragments direct-from-global (fragment-packed, coalesced 1KB/instr)
    // vf[ks2*2+dt] = fragment (kt = kb/16 + ks2, dg = kq*2 + dt), lane l.
    f16x8 vf[16];
    auto load_v = [&](int kb) {
        const size_t kt0 = (size_t)(kb >> 4);
#pragma unroll
        for (int ks2 = 0; ks2 < 8; ++ks2)
#pragma unroll
            for (int dt = 0; dt < 2; ++dt)
                vf[ks2 * 2 + dt] = *(const f16x8*)(
                    vp + (((kt0 + ks2) * 8 + kq * 2 + dt) * 64 + l) * 8);
    };

    // prologue: K tile 0 (full drain once)
    stage_k(0, lds_raw);
    __syncthreads();   // vmcnt(0) drain -> K tile 0 visible

    const int prow = pair * 32 + lm;  // this lane's q row within block

    for (int t = 0; t < NT_; ++t) {
        const int kb = t * BN_;
        char* kcur = lds_raw + (t & 1) * KB_BYTES;
        // issue DMA for next K tile FIRST (oldest in vmcnt FIFO), then vf.
        if (t + 1 < NT_) stage_k(kb + BN_, lds_raw + ((t + 1) & 1) * KB_BYTES);
        __builtin_amdgcn_sched_barrier(0);   // pin: DMAs precede vf loads
        load_v(kb);
        __builtin_amdgcn_sched_barrier(0);   // pin: vf loads precede S phase

        // ---- S^T tile (32k x 32q): A = K rows kq*32+lm (swizzled), B = qf ----
        f32x16 s;
#pragma unroll
        for (int j = 0; j < 16; ++j) s[j] = 0.0f;
#pragma unroll
        for (int ks = 0; ks < 16; ++ks) {
            const int gsw = (2 * ks + lh) ^ lm;   // 32 lanes -> 32 distinct granules
            f16x8 kf = *(const f16x8*)(kcur + (kq * 32 + lm) * 512 + gsw * 16);
            s = __builtin_amdgcn_mfma_f32_32x32x16_f16(kf, qf[ks], s, 0, 0, 0);
        }

        // ---- partial max over this wave's 32 k (per lane: q = lm) ----
        float pm = s[0];
#pragma unroll
        for (int j = 1; j < 16; ++j) pm = fmaxf(pm, s[j]);
        pm = fmaxf(pm, __shfl_xor(pm, 32, 64));
        if (lh == 0) smax[prow * 4 + kq] = pm;
        lgkm_barrier();    // B3: partial maxes visible; VMEM stays in flight

        const float4 m4 = *(const float4*)&smax[prow * 4];
        const float gm = fmaxf(fmaxf(m4.x, m4.y), fmaxf(m4.z, m4.w));
        const float mn = fmaxf(mstat, gm);
        const float alpha = __expf(mstat - mn);
        mstat = mn;

        // ---- exp (fp16-rounded for num/denom consistency), write P^T tile,
        //      partial sum ----
        float psum = 0.0f;
#pragma unroll
        for (int g = 0; g < 4; ++g) {
            u16x4 pk;
#pragma unroll
            for (int j = 0; j < 4; ++j) {
                const unsigned short hh = f2h(__expf(s[g * 4 + j] - mn));
                pk[j] = hh;
                psum += h2f(hh);
            }
            *(u16x4*)(pbuf + prow * PSTRIDE + (kq * 32 + 8 * g + 4 * lh) * 2) = pk;
        }
        psum += __shfl_xor(psum, 32, 64);
        if (lh == 0) ssum[prow * 4 + kq] = psum;
        vm16_lgkm_barrier();   // B4: P+ssum visible; 8 K-DMAs drained; vf flying

        const float4 s4 = *(const float4*)&ssum[prow * 4];
        lstat = lstat * alpha + (s4.x + s4.y) + (s4.z + s4.w);

        // ---- rescale O by alpha (per-lane scalar) ----
#pragma unroll
        for (int dt = 0; dt < 2; ++dt)
#pragma unroll
            for (int j = 0; j < 16; ++j) oacc[dt][j] *= alpha;

        // ---- O^T += V^T P^T : A = vf (registers), B = P frags from LDS ----
#pragma unroll
        for (int ks2 = 0; ks2 < 8; ++ks2) {
            f16x8 pf = *(const f16x8*)(pbuf + prow * PSTRIDE + ks2 * 32 + lh * 16);
#pragma unroll
            for (int dt = 0; dt < 2; ++dt)
                oacc[dt] = __builtin_amdgcn_mfma_f32_32x32x16_f16(vf[ks2 * 2 + dt], pf,
                                                                  oacc[dt], 0, 0, 0);
        }
    }

    // ---- finalize: divide by l (per-lane scalar), write out[b][q][d] fp32 ----
    const float linv = 1.0f / lstat;
    float* orow = out + (size_t)(batch * NQ_ + qb + pair * 32 + lm) * 256;
#pragma unroll
    for (int dt = 0; dt < 2; ++dt) {
#pragma unroll
        for (int g = 0; g < 4; ++g) {
            float4 o4;
            o4.x = oacc[dt][4 * g + 0] * linv;
            o4.y = oacc[dt][4 * g + 1] * linv;
            o4.z = oacc[dt][4 * g + 2] * linv;
            o4.w = oacc[dt][4 * g + 3] * linv;
            *(float4*)(orow + kq * 64 + dt * 32 + 8 * g + 4 * lh) = o4;
        }
    }
}

// ---------------------------------------------------------------------------
extern "C" void kernel_launch(void* const* d_in, const int* in_sizes, int n_in,
                              void* d_out, int out_size, void* d_ws, size_t ws_size,
                              hipStream_t stream) {
    const float* q  = (const float*)d_in[0];
    const float* k  = (const float*)d_in[1];
    const float* v  = (const float*)d_in[2];
    const float* Wq = (const float*)d_in[3];
    const float* bq = (const float*)d_in[4];
    const float* Wk = (const float*)d_in[5];
    const float* bk = (const float*)d_in[6];
    const float* Wv = (const float*)d_in[7];
    const float* bv = (const float*)d_in[8];
    float* out = (float*)d_out;

    unsigned short* wt      = (unsigned short*)d_ws;          // 3 * 256*256 fp16
    unsigned short* q_emb   = wt + 3 * 65536;                 // [16384][256]
    unsigned short* k_emb   = q_emb + (size_t)M_ * DH_;       // [16384][256]
    unsigned short* vpack   = k_emb + (size_t)M_ * DH_;       // [2][512][8][64][8]

    wt_conv<<<dim3(4, 4, 3), 256, 0, stream>>>(Wq, Wk, Wv, wt);
    proj<<<dim3(256, 3), 256, 0, stream>>>(q, k, v, bq, bk, bv, wt, q_emb, k_emb, vpack);
    flash<<<256, 512, 0, stream>>>(q_emb, k_emb, vpack, out);
}

// Round 5
// 314.704 us; speedup vs baseline: 1.0835x; 1.0835x over previous
//
#include <hip/hip_runtime.h>

// Problem constants
#define B_   2
#define NQ_  8192
#define NK_  8192
#define DIN_ 256
#define DH_  256
#define M_   (B_ * NQ_)   // 16384 flattened rows

typedef _Float16 f16x8 __attribute__((ext_vector_type(8)));
typedef unsigned short u16x8 __attribute__((ext_vector_type(8)));
typedef unsigned short u16x4 __attribute__((ext_vector_type(4)));
typedef unsigned int  u32x4 __attribute__((ext_vector_type(4)));
typedef float f32x16 __attribute__((ext_vector_type(16)));

// fp32 -> fp16 bits (RTNE via hardware cvt)
__device__ __forceinline__ unsigned short f2h(float f) {
    _Float16 h = (_Float16)f;
    return __builtin_bit_cast(unsigned short, h);
}
__device__ __forceinline__ float h2f(unsigned short u) {
    return (float)__builtin_bit_cast(_Float16, u);
}

// ---------------------------------------------------------------------------
// Kernel 1: weight convert + transpose via LDS tile (both sides coalesced).
// wt[mat][n][k] = fp16(W[mat][k][n]).  grid (4,4,3), block 256.  (unchanged)
// ---------------------------------------------------------------------------
__global__ void wt_conv(const float* __restrict__ Wq, const float* __restrict__ Wk,
                        const float* __restrict__ Wv, unsigned short* __restrict__ wt) {
    __shared__ float tile[64][65];
    const int mat = blockIdx.z;
    const int k0 = blockIdx.x * 64, n0 = blockIdx.y * 64;
    const float* W = (mat == 0) ? Wq : (mat == 1) ? Wk : Wv;
#pragma unroll
    for (int p = 0; p < 16; ++p) {
        const int idx = p * 256 + threadIdx.x;
        const int r = idx >> 6, c = idx & 63;
        tile[r][c] = W[(k0 + r) * 256 + n0 + c];
    }
    __syncthreads();
#pragma unroll
    for (int p = 0; p < 16; ++p) {
        const int idx = p * 256 + threadIdx.x;
        const int nr = idx >> 6, kc = idx & 63;
        wt[mat * 65536 + (n0 + nr) * 256 + k0 + kc] = f2h(tile[kc][nr]);
    }
}

// ---------------------------------------------------------------------------
// Kernel 2: projections (unchanged from v4).
// mat 2 (v): fragment-packed vpack[b][kt][dg][lane][j]; flash PV A-operand
// loads are contiguous 1KB per wave.
// ---------------------------------------------------------------------------
__global__ __launch_bounds__(256) void proj(
    const float* __restrict__ xq, const float* __restrict__ xk, const float* __restrict__ xv,
    const float* __restrict__ bq, const float* __restrict__ bk, const float* __restrict__ bv,
    const unsigned short* __restrict__ wt,
    unsigned short* __restrict__ q_emb, unsigned short* __restrict__ k_emb,
    unsigned short* __restrict__ vpack) {
    const int mat = blockIdx.y;
    const float* x    = (mat == 0) ? xq : (mat == 1) ? xk : xv;
    const float* bias = (mat == 0) ? bq : (mat == 1) ? bk : bv;
    const unsigned short* w = wt + mat * 65536;

    const int tid = threadIdx.x;
    const int l = tid & 63, wv = tid >> 6;
    const int pair = wv >> 1, h = wv & 1;
    const int lm = l & 31, lh = l >> 5;
    const int row0 = blockIdx.x * 64;
    const int m = row0 + pair * 32 + lm;

    f32x16 acc[4];
#pragma unroll
    for (int i = 0; i < 4; ++i)
#pragma unroll
        for (int j = 0; j < 16; ++j) acc[i][j] = 0.0f;

#pragma unroll
    for (int ks = 0; ks < 16; ++ks) {
        const float4* ap = (const float4*)(x + (size_t)m * 256 + ks * 16 + lh * 8);
        float4 a0 = ap[0], a1 = ap[1];
        u16x8 au;
        au[0] = f2h(a0.x); au[1] = f2h(a0.y); au[2] = f2h(a0.z); au[3] = f2h(a0.w);
        au[4] = f2h(a1.x); au[5] = f2h(a1.y); au[6] = f2h(a1.z); au[7] = f2h(a1.w);
        f16x8 af = __builtin_bit_cast(f16x8, au);
#pragma unroll
        for (int nt = 0; nt < 4; ++nt) {
            f16x8 bfr = *(const f16x8*)(w + (h * 128 + nt * 32 + lm) * 256 + ks * 16 + lh * 8);
            acc[nt] = __builtin_amdgcn_mfma_f32_32x32x16_f16(af, bfr, acc[nt], 0, 0, 0);
        }
    }

    if (mat < 2) {
        unsigned short* emb = (mat == 0) ? q_emb : k_emb;
#pragma unroll
        for (int nt = 0; nt < 4; ++nt) {
            const int n = h * 128 + nt * 32 + lm;
            const float bsv = bias[n];
#pragma unroll
            for (int r = 0; r < 16; ++r) {
                const int rl = (r & 3) + 8 * (r >> 2) + 4 * lh;
                emb[(size_t)(row0 + pair * 32 + rl) * 256 + n] = f2h(acc[nt][r] + bsv);
            }
        }
    } else {
        const int batch = row0 >> 13;
        const int m0 = (row0 & 8191) + pair * 32;   // v-row (k index) base
        unsigned short* vp = vpack + (size_t)batch * (512 * 8 * 64 * 8);
        const int base_kt = m0 >> 4;
#pragma unroll
        for (int nt = 0; nt < 4; ++nt) {
            const int dg = h * 4 + nt;              // d-group = n >> 5
            const int n = h * 128 + nt * 32 + lm;
            const float bsv = bias[n];
#pragma unroll
            for (int g = 0; g < 4; ++g) {
                u16x4 pk;
#pragma unroll
                for (int i = 0; i < 4; ++i) pk[i] = f2h(acc[nt][4 * g + i] + bsv);
                const int kt = base_kt + (g >> 1);
                const int lane = (g & 1) * 32 + lm;
                *(u16x4*)(vp + ((size_t)(kt * 8 + dg) * 64 + lane) * 8 + lh * 4) = pk;
            }
        }
    }
}

// ---------------------------------------------------------------------------
// Kernel 3: flash attention v6 = v4 structure (proven barriers) + PV role
// remap for V dedup.
//   - S-phase roles unchanged: wave (kq=wv>>1, pair=wv&1) computes the
//     32k x 32q S^T tile; cross-wave softmax via smax/ssum; P^T via pbuf.
//   - PV role NEW: wave wv owns d-group dg = wv (32 d rows), computes
//     O^T[32d x 64q] (both q-tiles).  vf loads: 8/wave, ZERO duplication
//     (was 16/wave with 2x dup) -> L2 traffic/iter 192KB -> 128KB.
//   - alpha for the O rescale is per-q-row; kq==0,lh==0 lanes publish
//     alph[64] in the softmax phase (identical value across kq waves);
//     read after B4.  linv published the same way after the loop.
//   - Barriers: plain __syncthreads (B3/B4), exactly as the 213us v4.
// ---------------------------------------------------------------------------
#define BN_ 128
#define NT_ (NK_ / BN_)                    // 64 iterations
#define KB_BYTES 65536                     // 128 rows x 512B (swizzled granules)
#define PSTRIDE 272                        // 64 rows x (256 + 16) : proven pad
#define PBYTES  (64 * PSTRIDE)             // 17408
#define STAT_OFF (2 * KB_BYTES + PBYTES)   // 148480
#define LDS_TOTAL (STAT_OFF + 2048)        // 150528 <= 160 KiB

__global__ __launch_bounds__(512, 2) void flash(
    const unsigned short* __restrict__ q_emb, const unsigned short* __restrict__ k_emb,
    const unsigned short* __restrict__ vpack, float* __restrict__ out) {
    __shared__ __align__(16) char lds_raw[LDS_TOTAL];
    char* pbuf = lds_raw + 2 * KB_BYTES;        // [64][272]
    float* smax = (float*)(lds_raw + STAT_OFF); // [2][32][4]  (256 floats? 64*4)
    float* ssum = smax + 256;                   // [64][4]
    float* alph = ssum + 256;                   // [64] per-q-row alpha
    float* linvb = alph + 64;                   // [64] per-q-row 1/l

    const int tid = threadIdx.x;
    const int l = tid & 63, wv = tid >> 6;      // wv 0..7
    const int kq = wv >> 1, pair = wv & 1;      // S-phase roles
    const int lm = l & 31, lh = l >> 5;

    const int bx = blockIdx.x;
    const int batch = bx >> 7;
    const int qb = (bx & 127) * 64;

    const unsigned short* kg = k_emb + (size_t)batch * NK_ * 256;
    const unsigned short* vp = vpack + (size_t)batch * (512 * 8 * 64 * 8);

    // Q fragments register-resident: q row = qb + pair*32 + lm, all 256 dims.
    const int mrow = batch * NQ_ + qb + pair * 32 + lm;
    f16x8 qf[16];
#pragma unroll
    for (int ks = 0; ks < 16; ++ks)
        qf[ks] = *(const f16x8*)(q_emb + (size_t)mrow * 256 + ks * 16 + lh * 8);

    // O^T accumulator (PV role): d rows = wv*32 + crow, q cols = qt*32 + lm.
    f32x16 oacc[2];
#pragma unroll
    for (int i = 0; i < 2; ++i)
#pragma unroll
        for (int j = 0; j < 16; ++j) oacc[i][j] = 0.0f;

    float mstat = -3.0e38f, lstat = 0.0f;

    // ---- K staging via global_load_lds (unchanged from v4) ----
    const int rlane = l >> 5;                  // +0/+1 row within 1KB chunk
    const int gl = l & 31;                     // linear granule this lane fills
    auto stage_k = [&](int kb, char* kdst) {
#pragma unroll
        for (int p = 0; p < 8; ++p) {
            const int r0 = wv * 16 + 2 * p;            // wave-uniform base row
            const int r = r0 + rlane;
            const int gsw = gl ^ (r & 31);             // source granule
            const unsigned short* src = kg + (size_t)(kb + r) * 256 + gsw * 8;
            __builtin_amdgcn_global_load_lds(
                (const __attribute__((address_space(1))) void*)src,
                (__attribute__((address_space(3))) void*)(kdst + r0 * 512),
                16, 0, 0);
        }
    };

    // ---- V fragments direct-from-global, DEDUPED: dg = wv, 8 frags/wave.
    f16x8 vf[8];
    auto load_v = [&](int kb) {
        const size_t kt0 = (size_t)(kb >> 4);
#pragma unroll
        for (int ks2 = 0; ks2 < 8; ++ks2)
            vf[ks2] = *(const f16x8*)(vp + (((kt0 + ks2) * 8 + wv) * 64 + l) * 8);
    };

    // prologue: K tile 0 (full drain once)
    stage_k(0, lds_raw);
    __syncthreads();   // vmcnt(0) drain -> K tile 0 visible

    const int prow = pair * 32 + lm;  // this lane's S-role q row within block

    for (int t = 0; t < NT_; ++t) {
        const int kb = t * BN_;
        char* kcur = lds_raw + (t & 1) * KB_BYTES;
        // issue DMA for next K tile, then this tile's vf loads (v4 pattern)
        if (t + 1 < NT_) stage_k(kb + BN_, lds_raw + ((t + 1) & 1) * KB_BYTES);
        load_v(kb);

        // ---- S^T tile (32k x 32q): A = K rows kq*32+lm (swizzled), B = qf ----
        f32x16 s;
#pragma unroll
        for (int j = 0; j < 16; ++j) s[j] = 0.0f;
#pragma unroll
        for (int ks = 0; ks < 16; ++ks) {
            const int gsw = (2 * ks + lh) ^ lm;   // 32 lanes -> 32 distinct granules
            f16x8 kf = *(const f16x8*)(kcur + (kq * 32 + lm) * 512 + gsw * 16);
            s = __builtin_amdgcn_mfma_f32_32x32x16_f16(kf, qf[ks], s, 0, 0, 0);
        }

        // ---- partial max over this wave's 32 k (per lane: q = lm) ----
        float pm = s[0];
#pragma unroll
        for (int j = 1; j < 16; ++j) pm = fmaxf(pm, s[j]);
        pm = fmaxf(pm, __shfl_xor(pm, 32, 64));
        if (lh == 0) smax[prow * 4 + kq] = pm;
        __syncthreads();   // B3: partial maxes visible (drains VMEM too — v4)

        const float4 m4 = *(const float4*)&smax[prow * 4];
        const float gm = fmaxf(fmaxf(m4.x, m4.y), fmaxf(m4.z, m4.w));
        const float mn = fmaxf(mstat, gm);
        const float alpha = __expf(mstat - mn);
        mstat = mn;
        if (kq == 0 && lh == 0) alph[prow] = alpha;   // publish per-q-row alpha

        // ---- exp (fp16-rounded for num/denom consistency), write P^T tile,
        //      partial sum ----
        float psum = 0.0f;
#pragma unroll
        for (int g = 0; g < 4; ++g) {
            u16x4 pk;
#pragma unroll
            for (int j = 0; j < 4; ++j) {
                const unsigned short hh = f2h(__expf(s[g * 4 + j] - mn));
                pk[j] = hh;
                psum += h2f(hh);
            }
            *(u16x4*)(pbuf + prow * PSTRIDE + (kq * 32 + 8 * g + 4 * lh) * 2) = pk;
        }
        psum += __shfl_xor(psum, 32, 64);
        if (lh == 0) ssum[prow * 4 + kq] = psum;
        __syncthreads();   // B4: P tiles + partial sums + alph visible

        const float4 s4 = *(const float4*)&ssum[prow * 4];
        lstat = lstat * alpha + (s4.x + s4.y) + (s4.z + s4.w);

        // ---- rescale O by per-q-row alpha (cols q = qt*32 + lm) ----
        const float a0 = alph[lm];
        const float a1 = alph[lm + 32];
#pragma unroll
        for (int j = 0; j < 16; ++j) oacc[0][j] *= a0;
#pragma unroll
        for (int j = 0; j < 16; ++j) oacc[1][j] *= a1;

        // ---- O^T += V^T P^T : A = vf (dg = wv, registers), B = P frags for
        //      both q-tiles from LDS ----
#pragma unroll
        for (int ks2 = 0; ks2 < 8; ++ks2) {
            const f16x8 vfr = vf[ks2];
            f16x8 pf0 = *(const f16x8*)(pbuf + lm * PSTRIDE + ks2 * 32 + lh * 16);
            f16x8 pf1 = *(const f16x8*)(pbuf + (lm + 32) * PSTRIDE + ks2 * 32 + lh * 16);
            oacc[0] = __builtin_amdgcn_mfma_f32_32x32x16_f16(vfr, pf0, oacc[0], 0, 0, 0);
            oacc[1] = __builtin_amdgcn_mfma_f32_32x32x16_f16(vfr, pf1, oacc[1], 0, 0, 0);
        }
    }

    // ---- publish per-q-row 1/l, then write out[b][q][d] fp32 ----
    if (kq == 0 && lh == 0) linvb[prow] = 1.0f / lstat;
    __syncthreads();
    const float linv0 = linvb[lm];
    const float linv1 = linvb[lm + 32];
#pragma unroll
    for (int qt = 0; qt < 2; ++qt) {
        const float lv = qt ? linv1 : linv0;
        float* orow = out + (size_t)(batch * NQ_ + qb + qt * 32 + lm) * 256 + wv * 32;
#pragma unroll
        for (int g = 0; g < 4; ++g) {
            float4 o4;
            o4.x = oacc[qt][4 * g + 0] * lv;
            o4.y = oacc[qt][4 * g + 1] * lv;
            o4.z = oacc[qt][4 * g + 2] * lv;
            o4.w = oacc[qt][4 * g + 3] * lv;
            *(float4*)(orow + 8 * g + 4 * lh) = o4;
        }
    }
}

// ---------------------------------------------------------------------------
extern "C" void kernel_launch(void* const* d_in, const int* in_sizes, int n_in,
                              void* d_out, int out_size, void* d_ws, size_t ws_size,
                              hipStream_t stream) {
    const float* q  = (const float*)d_in[0];
    const float* k  = (const float*)d_in[1];
    const float* v  = (const float*)d_in[2];
    const float* Wq = (const float*)d_in[3];
    const float* bq = (const float*)d_in[4];
    const float* Wk = (const float*)d_in[5];
    const float* bk = (const float*)d_in[6];
    const float* Wv = (const float*)d_in[7];
    const float* bv = (const float*)d_in[8];
    float* out = (float*)d_out;

    unsigned short* wt      = (unsigned short*)d_ws;          // 3 * 256*256 fp16
    unsigned short* q_emb   = wt + 3 * 65536;                 // [16384][256]
    unsigned short* k_emb   = q_emb + (size_t)M_ * DH_;       // [16384][256]
    unsigned short* vpack   = k_emb + (size_t)M_ * DH_;       // [2][512][8][64][8]

    wt_conv<<<dim3(4, 4, 3), 256, 0, stream>>>(Wq, Wk, Wv, wt);
    proj<<<dim3(256, 3), 256, 0, stream>>>(q, k, v, bq, bk, bv, wt, q_emb, k_emb, vpack);
    flash<<<256, 512, 0, stream>>>(q_emb, k_emb, vpack, out);
}

// Round 6
// 286.286 us; speedup vs baseline: 1.1911x; 1.0993x over previous
//
#include <hip/hip_runtime.h>

// Problem constants
#define B_   2
#define NQ_  8192
#define NK_  8192
#define DIN_ 256
#define DH_  256
#define M_   (B_ * NQ_)   // 16384 flattened rows

typedef _Float16 f16x8 __attribute__((ext_vector_type(8)));
typedef unsigned short u16x8 __attribute__((ext_vector_type(8)));
typedef unsigned short u16x4 __attribute__((ext_vector_type(4)));
typedef unsigned int  u32x4 __attribute__((ext_vector_type(4)));
typedef float f32x16 __attribute__((ext_vector_type(16)));

// fp32 -> fp16 bits (RTNE via hardware cvt)
__device__ __forceinline__ unsigned short f2h(float f) {
    _Float16 h = (_Float16)f;
    return __builtin_bit_cast(unsigned short, h);
}
__device__ __forceinline__ float h2f(unsigned short u) {
    return (float)__builtin_bit_cast(_Float16, u);
}

// ---------------------------------------------------------------------------
// Kernel 1: weight convert + repack into MFMA B-fragment order.
// wpack[mat][ks][ng][lane][j] = fp16(W[k = ks*16 + (lane>>5)*8 + j]
//                                    [n = ng*32 + (lane&31)])
// so proj's B loads are contiguous 1KB per wave fragment.
// grid (4,4,3), block 256; LDS tile transpose keeps global reads coalesced.
// ---------------------------------------------------------------------------
__global__ void wt_conv(const float* __restrict__ Wq, const float* __restrict__ Wk,
                        const float* __restrict__ Wv, unsigned short* __restrict__ wpack) {
    __shared__ float tile[64][65];
    const int mat = blockIdx.z;
    const int k0 = blockIdx.x * 64, n0 = blockIdx.y * 64;
    const float* W = (mat == 0) ? Wq : (mat == 1) ? Wk : Wv;
#pragma unroll
    for (int p = 0; p < 16; ++p) {
        const int idx = p * 256 + threadIdx.x;
        const int r = idx >> 6, c = idx & 63;    // r = kk, c = nn
        tile[r][c] = W[(k0 + r) * 256 + n0 + c];
    }
    __syncthreads();
    unsigned short* wp = wpack + mat * 65536;
#pragma unroll
    for (int p = 0; p < 2; ++p) {
        const int e = p * 256 + threadIdx.x;     // 0..511
        const int kk8 = e >> 6;                  // 8-k group 0..7
        const int nn = e & 63;
        const int ks = (k0 >> 4) + (kk8 >> 1);
        const int lh = kk8 & 1;
        const int ng = (n0 >> 5) + (nn >> 5);
        const int l = (nn & 31) + 32 * lh;
        u16x8 val;
#pragma unroll
        for (int j = 0; j < 8; ++j) val[j] = f2h(tile[kk8 * 8 + j][nn]);
        *(u16x8*)(wp + ((size_t)(ks * 8 + ng) * 64 + l) * 8) = val;
    }
}

// ---------------------------------------------------------------------------
// Kernel 2: projections v7.  X[16384,256] fp32 @ W[256,256] + b -> fp16.
//   - x staged via LDS (fp16, XOR granule swizzle): global reads fully
//     coalesced (32B/lane float4-pairs), A-frags via conflict-free
//     ds_read_b128 (2-way = free).
//   - W streamed from wpack: contiguous 1KB wave fragments (L2-resident).
//   - Epilogue identical to v6 (q/k row-major; v fragment-packed vpack).
// ---------------------------------------------------------------------------
__global__ __launch_bounds__(256) void proj(
    const float* __restrict__ xq, const float* __restrict__ xk, const float* __restrict__ xv,
    const float* __restrict__ bq, const float* __restrict__ bk, const float* __restrict__ bv,
    const unsigned short* __restrict__ wpack,
    unsigned short* __restrict__ q_emb, unsigned short* __restrict__ k_emb,
    unsigned short* __restrict__ vpack) {
    __shared__ __align__(16) unsigned short xt[64 * 256];   // 32 KB fp16, swizzled
    const int mat = blockIdx.y;
    const float* x    = (mat == 0) ? xq : (mat == 1) ? xk : xv;
    const float* bias = (mat == 0) ? bq : (mat == 1) ? bk : bv;
    const unsigned short* wp = wpack + mat * 65536;

    const int tid = threadIdx.x;
    const int l = tid & 63, wv = tid >> 6;
    const int pair = wv >> 1, h = wv & 1;
    const int lm = l & 31, lh = l >> 5;
    const int row0 = blockIdx.x * 64;

    // ---- stage x[row0..row0+63][0..255] -> fp16 LDS, granule-XOR-swizzled.
    // granule = 8 halves = 16B.  LDS[r][g ^ (r&31)] = x[r][g].
    {
        const float* xb = x + (size_t)row0 * 256;
#pragma unroll
        for (int p = 0; p < 8; ++p) {
            const int idx = p * 256 + tid;       // 0..2047
            const int r = idx >> 5;              // row 0..63
            const int c8 = idx & 31;             // granule 0..31
            const float4* ap = (const float4*)(xb + r * 256 + c8 * 8);
            float4 a0 = ap[0], a1 = ap[1];
            u16x8 au;
            au[0] = f2h(a0.x); au[1] = f2h(a0.y); au[2] = f2h(a0.z); au[3] = f2h(a0.w);
            au[4] = f2h(a1.x); au[5] = f2h(a1.y); au[6] = f2h(a1.z); au[7] = f2h(a1.w);
            *(u16x8*)(xt + r * 256 + (c8 ^ (r & 31)) * 8) = au;
        }
    }
    __syncthreads();

    f32x16 acc[4];
#pragma unroll
    for (int i = 0; i < 4; ++i)
#pragma unroll
        for (int j = 0; j < 16; ++j) acc[i][j] = 0.0f;

#pragma unroll
    for (int ks = 0; ks < 16; ++ks) {
        // A frag: row = pair*32+lm, halves ks*16+lh*8..+7 = granule ks*2+lh.
        f16x8 af = *(const f16x8*)(xt + (pair * 32 + lm) * 256 +
                                   (((ks * 2 + lh) ^ lm) * 8));
#pragma unroll
        for (int nt = 0; nt < 4; ++nt) {
            f16x8 bfr = *(const f16x8*)(wp + ((size_t)(ks * 8 + h * 4 + nt) * 64 + l) * 8);
            acc[nt] = __builtin_amdgcn_mfma_f32_32x32x16_f16(af, bfr, acc[nt], 0, 0, 0);
        }
    }

    if (mat < 2) {
        unsigned short* emb = (mat == 0) ? q_emb : k_emb;
#pragma unroll
        for (int nt = 0; nt < 4; ++nt) {
            const int n = h * 128 + nt * 32 + lm;
            const float bsv = bias[n];
#pragma unroll
            for (int r = 0; r < 16; ++r) {
                const int rl = (r & 3) + 8 * (r >> 2) + 4 * lh;
                emb[(size_t)(row0 + pair * 32 + rl) * 256 + n] = f2h(acc[nt][r] + bsv);
            }
        }
    } else {
        const int batch = row0 >> 13;
        const int m0 = (row0 & 8191) + pair * 32;   // v-row (k index) base
        unsigned short* vp = vpack + (size_t)batch * (512 * 8 * 64 * 8);
        const int base_kt = m0 >> 4;
#pragma unroll
        for (int nt = 0; nt < 4; ++nt) {
            const int dg = h * 4 + nt;              // d-group = n >> 5
            const int n = h * 128 + nt * 32 + lm;
            const float bsv = bias[n];
#pragma unroll
            for (int g = 0; g < 4; ++g) {
                u16x4 pk;
#pragma unroll
                for (int i = 0; i < 4; ++i) pk[i] = f2h(acc[nt][4 * g + i] + bsv);
                const int kt = base_kt + (g >> 1);
                const int lane = (g & 1) * 32 + lm;
                *(u16x4*)(vp + ((size_t)(kt * 8 + dg) * 64 + lane) * 8 + lh * 4) = pk;
            }
        }
    }
}

// ---------------------------------------------------------------------------
// Kernel 3: flash attention v6 (unchanged — proven 193 us).
//   - S-phase roles: wave (kq=wv>>1, pair=wv&1) computes 32k x 32q S^T tile.
//   - PV role: wave wv owns d-group dg = wv, O^T[32d x 64q], vf deduped.
//   - K staged via global_load_lds double buffer, source-side XOR swizzle.
//   - Barriers: plain __syncthreads (B3/B4).
// ---------------------------------------------------------------------------
#define BN_ 128
#define NT_ (NK_ / BN_)                    // 64 iterations
#define KB_BYTES 65536                     // 128 rows x 512B (swizzled granules)
#define PSTRIDE 272                        // 64 rows x (256 + 16) : proven pad
#define PBYTES  (64 * PSTRIDE)             // 17408
#define STAT_OFF (2 * KB_BYTES + PBYTES)   // 148480
#define LDS_TOTAL (STAT_OFF + 2048)        // 150528 <= 160 KiB

__global__ __launch_bounds__(512, 2) void flash(
    const unsigned short* __restrict__ q_emb, const unsigned short* __restrict__ k_emb,
    const unsigned short* __restrict__ vpack, float* __restrict__ out) {
    __shared__ __align__(16) char lds_raw[LDS_TOTAL];
    char* pbuf = lds_raw + 2 * KB_BYTES;        // [64][272]
    float* smax = (float*)(lds_raw + STAT_OFF); // [64][4]
    float* ssum = smax + 256;                   // [64][4]
    float* alph = ssum + 256;                   // [64] per-q-row alpha
    float* linvb = alph + 64;                   // [64] per-q-row 1/l

    const int tid = threadIdx.x;
    const int l = tid & 63, wv = tid >> 6;      // wv 0..7
    const int kq = wv >> 1, pair = wv & 1;      // S-phase roles
    const int lm = l & 31, lh = l >> 5;

    const int bx = blockIdx.x;
    const int batch = bx >> 7;
    const int qb = (bx & 127) * 64;

    const unsigned short* kg = k_emb + (size_t)batch * NK_ * 256;
    const unsigned short* vp = vpack + (size_t)batch * (512 * 8 * 64 * 8);

    // Q fragments register-resident: q row = qb + pair*32 + lm, all 256 dims.
    const int mrow = batch * NQ_ + qb + pair * 32 + lm;
    f16x8 qf[16];
#pragma unroll
    for (int ks = 0; ks < 16; ++ks)
        qf[ks] = *(const f16x8*)(q_emb + (size_t)mrow * 256 + ks * 16 + lh * 8);

    // O^T accumulator (PV role): d rows = wv*32 + crow, q cols = qt*32 + lm.
    f32x16 oacc[2];
#pragma unroll
    for (int i = 0; i < 2; ++i)
#pragma unroll
        for (int j = 0; j < 16; ++j) oacc[i][j] = 0.0f;

    float mstat = -3.0e38f, lstat = 0.0f;

    // ---- K staging via global_load_lds ----
    const int rlane = l >> 5;                  // +0/+1 row within 1KB chunk
    const int gl = l & 31;                     // linear granule this lane fills
    auto stage_k = [&](int kb, char* kdst) {
#pragma unroll
        for (int p = 0; p < 8; ++p) {
            const int r0 = wv * 16 + 2 * p;            // wave-uniform base row
            const int r = r0 + rlane;
            const int gsw = gl ^ (r & 31);             // source granule
            const unsigned short* src = kg + (size_t)(kb + r) * 256 + gsw * 8;
            __builtin_amdgcn_global_load_lds(
                (const __attribute__((address_space(1))) void*)src,
                (__attribute__((address_space(3))) void*)(kdst + r0 * 512),
                16, 0, 0);
        }
    };

    // ---- V fragments direct-from-global, DEDUPED: dg = wv, 8 frags/wave.
    f16x8 vf[8];
    auto load_v = [&](int kb) {
        const size_t kt0 = (size_t)(kb >> 4);
#pragma unroll
        for (int ks2 = 0; ks2 < 8; ++ks2)
            vf[ks2] = *(const f16x8*)(vp + (((kt0 + ks2) * 8 + wv) * 64 + l) * 8);
    };

    // prologue: K tile 0 (full drain once)
    stage_k(0, lds_raw);
    __syncthreads();   // vmcnt(0) drain -> K tile 0 visible

    const int prow = pair * 32 + lm;  // this lane's S-role q row within block

    for (int t = 0; t < NT_; ++t) {
        const int kb = t * BN_;
        char* kcur = lds_raw + (t & 1) * KB_BYTES;
        // issue DMA for next K tile, then this tile's vf loads
        if (t + 1 < NT_) stage_k(kb + BN_, lds_raw + ((t + 1) & 1) * KB_BYTES);
        load_v(kb);

        // ---- S^T tile (32k x 32q): A = K rows kq*32+lm (swizzled), B = qf ----
        f32x16 s;
#pragma unroll
        for (int j = 0; j < 16; ++j) s[j] = 0.0f;
#pragma unroll
        for (int ks = 0; ks < 16; ++ks) {
            const int gsw = (2 * ks + lh) ^ lm;   // 32 lanes -> 32 distinct granules
            f16x8 kf = *(const f16x8*)(kcur + (kq * 32 + lm) * 512 + gsw * 16);
            s = __builtin_amdgcn_mfma_f32_32x32x16_f16(kf, qf[ks], s, 0, 0, 0);
        }

        // ---- partial max over this wave's 32 k (per lane: q = lm) ----
        float pm = s[0];
#pragma unroll
        for (int j = 1; j < 16; ++j) pm = fmaxf(pm, s[j]);
        pm = fmaxf(pm, __shfl_xor(pm, 32, 64));
        if (lh == 0) smax[prow * 4 + kq] = pm;
        __syncthreads();   // B3: partial maxes visible

        const float4 m4 = *(const float4*)&smax[prow * 4];
        const float gm = fmaxf(fmaxf(m4.x, m4.y), fmaxf(m4.z, m4.w));
        const float mn = fmaxf(mstat, gm);
        const float alpha = __expf(mstat - mn);
        mstat = mn;
        if (kq == 0 && lh == 0) alph[prow] = alpha;   // publish per-q-row alpha

        // ---- exp (fp16-rounded for num/denom consistency), write P^T tile,
        //      partial sum ----
        float psum = 0.0f;
#pragma unroll
        for (int g = 0; g < 4; ++g) {
            u16x4 pk;
#pragma unroll
            for (int j = 0; j < 4; ++j) {
                const unsigned short hh = f2h(__expf(s[g * 4 + j] - mn));
                pk[j] = hh;
                psum += h2f(hh);
            }
            *(u16x4*)(pbuf + prow * PSTRIDE + (kq * 32 + 8 * g + 4 * lh) * 2) = pk;
        }
        psum += __shfl_xor(psum, 32, 64);
        if (lh == 0) ssum[prow * 4 + kq] = psum;
        __syncthreads();   // B4: P tiles + partial sums + alph visible

        const float4 s4 = *(const float4*)&ssum[prow * 4];
        lstat = lstat * alpha + (s4.x + s4.y) + (s4.z + s4.w);

        // ---- rescale O by per-q-row alpha (cols q = qt*32 + lm) ----
        const float a0 = alph[lm];
        const float a1 = alph[lm + 32];
#pragma unroll
        for (int j = 0; j < 16; ++j) oacc[0][j] *= a0;
#pragma unroll
        for (int j = 0; j < 16; ++j) oacc[1][j] *= a1;

        // ---- O^T += V^T P^T : A = vf (dg = wv, registers), B = P frags for
        //      both q-tiles from LDS ----
#pragma unroll
        for (int ks2 = 0; ks2 < 8; ++ks2) {
            const f16x8 vfr = vf[ks2];
            f16x8 pf0 = *(const f16x8*)(pbuf + lm * PSTRIDE + ks2 * 32 + lh * 16);
            f16x8 pf1 = *(const f16x8*)(pbuf + (lm + 32) * PSTRIDE + ks2 * 32 + lh * 16);
            oacc[0] = __builtin_amdgcn_mfma_f32_32x32x16_f16(vfr, pf0, oacc[0], 0, 0, 0);
            oacc[1] = __builtin_amdgcn_mfma_f32_32x32x16_f16(vfr, pf1, oacc[1], 0, 0, 0);
        }
    }

    // ---- publish per-q-row 1/l, then write out[b][q][d] fp32 ----
    if (kq == 0 && lh == 0) linvb[prow] = 1.0f / lstat;
    __syncthreads();
    const float linv0 = linvb[lm];
    const float linv1 = linvb[lm + 32];
#pragma unroll
    for (int qt = 0; qt < 2; ++qt) {
        const float lv = qt ? linv1 : linv0;
        float* orow = out + (size_t)(batch * NQ_ + qb + qt * 32 + lm) * 256 + wv * 32;
#pragma unroll
        for (int g = 0; g < 4; ++g) {
            float4 o4;
            o4.x = oacc[qt][4 * g + 0] * lv;
            o4.y = oacc[qt][4 * g + 1] * lv;
            o4.z = oacc[qt][4 * g + 2] * lv;
            o4.w = oacc[qt][4 * g + 3] * lv;
            *(float4*)(orow + 8 * g + 4 * lh) = o4;
        }
    }
}

// ---------------------------------------------------------------------------
extern "C" void kernel_launch(void* const* d_in, const int* in_sizes, int n_in,
                              void* d_out, int out_size, void* d_ws, size_t ws_size,
                              hipStream_t stream) {
    const float* q  = (const float*)d_in[0];
    const float* k  = (const float*)d_in[1];
    const float* v  = (const float*)d_in[2];
    const float* Wq = (const float*)d_in[3];
    const float* bq = (const float*)d_in[4];
    const float* Wk = (const float*)d_in[5];
    const float* bk = (const float*)d_in[6];
    const float* Wv = (const float*)d_in[7];
    const float* bv = (const float*)d_in[8];
    float* out = (float*)d_out;

    unsigned short* wpack   = (unsigned short*)d_ws;          // 3 * 16*8*64*8 fp16
    unsigned short* q_emb   = wpack + 3 * 65536;              // [16384][256]
    unsigned short* k_emb   = q_emb + (size_t)M_ * DH_;       // [16384][256]
    unsigned short* vpack   = k_emb + (size_t)M_ * DH_;       // [2][512][8][64][8]

    wt_conv<<<dim3(4, 4, 3), 256, 0, stream>>>(Wq, Wk, Wv, wpack);
    proj<<<dim3(256, 3), 256, 0, stream>>>(q, k, v, bq, bk, bv, wpack, q_emb, k_emb, vpack);
    flash<<<256, 512, 0, stream>>>(q_emb, k_emb, vpack, out);
}